// Round 1
// baseline (1140.851 us; speedup 1.0000x reference)
//
#include <hip/hip_runtime.h>
#include <cstddef>

#define CUR_ELEMS (25600 * 256)   // [50*512][256] f32 scratch (cur, then ff0 in place)

// ---------------------------------------------------------------------------
// K0: one-time weight transposes into workspace (k-major for sparse column sums)
// ---------------------------------------------------------------------------
__global__ __launch_bounds__(256) void k0_transpose(
    const float* __restrict__ Wf, const float* __restrict__ Wr,
    const float* __restrict__ Wo, float* __restrict__ ws) {
  int tid = blockIdx.x * blockDim.x + threadIdx.x;
  float* Wr0T = ws + CUR_ELEMS;
  float* Wf1T = Wr0T + 65536;
  float* Wr1T = Wf1T + 65536;
  float* WoT  = Wr1T + 65536;
  if (tid < 65536) {
    int k = tid >> 8, h = tid & 255;
    Wr0T[tid] = Wr[h * 256 + k];
  } else if (tid < 131072) {
    int i = tid - 65536; int k = i >> 8, h = i & 255;
    Wf1T[i] = Wf[65536 + h * 256 + k];
  } else if (tid < 196608) {
    int i = tid - 131072; int k = i >> 8, h = i & 255;
    Wr1T[i] = Wr[65536 + h * 256 + k];
  } else if (tid < 201728) {
    int i = tid - 196608; int k = i / 20, j = i - k * 20;
    WoT[i] = Wo[j * 256 + k];
  }
}

// ---------------------------------------------------------------------------
// K1: cur[t][b][h] = sum_i x[b, t-d_i, :] . Wd[i][h][:]  + sum_i bd[i][h]
// t-major output; per-tile delay skip (t < d_i contributes nothing).
// 128(b) x 128(h) tile, 256 threads, 8x8 micro-tile, K-chunks of 16.
// ---------------------------------------------------------------------------
__global__ __launch_bounds__(256) void k1_cur(
    const float* __restrict__ x, const float* __restrict__ Wd,
    const float* __restrict__ bd, float* __restrict__ cur) {
  __shared__ float As[16][132];
  __shared__ float Bs[16][132];
  const int t  = blockIdx.y;
  const int bt = blockIdx.x >> 1, ht = blockIdx.x & 1;
  const int b0 = bt * 128, h0 = ht * 128;
  const int tid = threadIdx.x;
  const int tx = tid & 15, ty = tid >> 4;
  const int r = tid & 127, half = tid >> 7;

  float acc[8][8];
#pragma unroll
  for (int i = 0; i < 8; ++i)
#pragma unroll
    for (int j = 0; j < 8; ++j) acc[i][j] = 0.f;

  const int DEL[3] = {0, 16, 32};
#pragma unroll 1
  for (int di = 0; di < 3; ++di) {
    const int d = DEL[di];
    if (t < d) continue;
    const int tsrc = t - d;
    const float* Arow = x + ((size_t)(b0 + r) * 50 + tsrc) * 700;
    const float* Brow = Wd + (size_t)di * 179200 + (size_t)(h0 + r) * 700;
#pragma unroll 1
    for (int k0 = 0; k0 < 700; k0 += 16) {
#pragma unroll
      for (int e = 0; e < 2; ++e) {
        const int kk0 = half * 8 + e * 4;
        float4 av, bv;
        if (k0 + kk0 + 3 < 700) {
          av = *(const float4*)(Arow + k0 + kk0);
          bv = *(const float4*)(Brow + k0 + kk0);
        } else {
          av = make_float4(0.f, 0.f, 0.f, 0.f);
          bv = make_float4(0.f, 0.f, 0.f, 0.f);
        }
        As[kk0 + 0][r] = av.x; As[kk0 + 1][r] = av.y;
        As[kk0 + 2][r] = av.z; As[kk0 + 3][r] = av.w;
        Bs[kk0 + 0][r] = bv.x; Bs[kk0 + 1][r] = bv.y;
        Bs[kk0 + 2][r] = bv.z; Bs[kk0 + 3][r] = bv.w;
      }
      __syncthreads();
#pragma unroll
      for (int kk = 0; kk < 16; ++kk) {
        const float4 a0 = *(const float4*)&As[kk][ty * 4];
        const float4 a1 = *(const float4*)&As[kk][64 + ty * 4];
        const float4 c0 = *(const float4*)&Bs[kk][tx * 4];
        const float4 c1 = *(const float4*)&Bs[kk][64 + tx * 4];
        const float ar[8] = {a0.x, a0.y, a0.z, a0.w, a1.x, a1.y, a1.z, a1.w};
        const float br[8] = {c0.x, c0.y, c0.z, c0.w, c1.x, c1.y, c1.z, c1.w};
#pragma unroll
        for (int rr = 0; rr < 8; ++rr)
#pragma unroll
          for (int cc = 0; cc < 8; ++cc) acc[rr][cc] += ar[rr] * br[cc];
      }
      __syncthreads();
    }
  }
  float bias[8];
#pragma unroll
  for (int q = 0; q < 2; ++q)
#pragma unroll
    for (int c = 0; c < 4; ++c) {
      const int col = h0 + q * 64 + tx * 4 + c;
      bias[q * 4 + c] = bd[col] + bd[256 + col] + bd[512 + col];
    }
#pragma unroll
  for (int p = 0; p < 2; ++p)
#pragma unroll
    for (int rr = 0; rr < 4; ++rr) {
      const int row = b0 + p * 64 + ty * 4 + rr;
      float* dst = cur + ((size_t)t * 512 + row) * 256 + h0;
      const int ai = p * 4 + rr;
      float4 v0 = make_float4(acc[ai][0] + bias[0], acc[ai][1] + bias[1],
                              acc[ai][2] + bias[2], acc[ai][3] + bias[3]);
      float4 v1 = make_float4(acc[ai][4] + bias[4], acc[ai][5] + bias[5],
                              acc[ai][6] + bias[6], acc[ai][7] + bias[7]);
      *(float4*)(dst + tx * 4) = v0;
      *(float4*)(dst + 64 + tx * 4) = v1;
    }
}

// ---------------------------------------------------------------------------
// K1b: ff0[m][h] = cur[m][:] . Wf0[h][:] + bf0[h], IN PLACE over cur.
// Each block owns 64 full rows (reads and writes only its own rows -> safe).
// ---------------------------------------------------------------------------
__global__ __launch_bounds__(256) void k1b_ff0(
    const float* __restrict__ Wf, const float* __restrict__ bf,
    float* __restrict__ cur) {
  __shared__ float As[16][68];
  __shared__ float Bs[16][260];
  const int m0 = blockIdx.x * 64;
  const int tid = threadIdx.x;
  const int tx = tid & 15, ty = tid >> 4;
  const int lr = tid & 63, akk = (tid >> 6) * 4;

  float acc[4][16];
#pragma unroll
  for (int i = 0; i < 4; ++i)
#pragma unroll
    for (int j = 0; j < 16; ++j) acc[i][j] = 0.f;

#pragma unroll 1
  for (int k0 = 0; k0 < 256; k0 += 16) {
    float4 av = *(const float4*)(cur + (size_t)(m0 + lr) * 256 + k0 + akk);
    As[akk + 0][lr] = av.x; As[akk + 1][lr] = av.y;
    As[akk + 2][lr] = av.z; As[akk + 3][lr] = av.w;
#pragma unroll
    for (int e = 0; e < 4; ++e) {
      const int hh = e * 64 + lr;
      float4 bv = *(const float4*)(Wf + (size_t)hh * 256 + k0 + akk);
      Bs[akk + 0][hh] = bv.x; Bs[akk + 1][hh] = bv.y;
      Bs[akk + 2][hh] = bv.z; Bs[akk + 3][hh] = bv.w;
    }
    __syncthreads();
#pragma unroll
    for (int kk = 0; kk < 16; ++kk) {
      const float4 a = *(const float4*)&As[kk][ty * 4];
      const float ar[4] = {a.x, a.y, a.z, a.w};
#pragma unroll
      for (int q = 0; q < 4; ++q) {
        const float4 bq = *(const float4*)&Bs[kk][q * 64 + tx * 4];
        const float br[4] = {bq.x, bq.y, bq.z, bq.w};
#pragma unroll
        for (int rr = 0; rr < 4; ++rr)
#pragma unroll
          for (int cc = 0; cc < 4; ++cc)
            acc[rr][q * 4 + cc] += ar[rr] * br[cc];
      }
    }
    __syncthreads();
  }
  float bias[16];
#pragma unroll
  for (int q = 0; q < 4; ++q)
#pragma unroll
    for (int c = 0; c < 4; ++c) bias[q * 4 + c] = bf[q * 64 + tx * 4 + c];
#pragma unroll
  for (int rr = 0; rr < 4; ++rr) {
    float* dst = cur + (size_t)(m0 + ty * 4 + rr) * 256;
#pragma unroll
    for (int q = 0; q < 4; ++q) {
      float4 v = make_float4(acc[rr][q * 4 + 0] + bias[q * 4 + 0],
                             acc[rr][q * 4 + 1] + bias[q * 4 + 1],
                             acc[rr][q * 4 + 2] + bias[q * 4 + 2],
                             acc[rr][q * 4 + 3] + bias[q * 4 + 3]);
      *(float4*)(dst + q * 64 + tx * 4) = v;
    }
  }
}

// ---------------------------------------------------------------------------
// K2: 50-step recurrent scan. One block per batch row (512 blocks, 256 thr).
// Spike GEMVs done as sparse column sums over ballot-compacted active lists.
// Membranes live in registers; spikes/lists in LDS. 5 syncthreads per step.
// ---------------------------------------------------------------------------
__global__ __launch_bounds__(256) void k2_scan(
    const float* __restrict__ ff0, const float* __restrict__ Wr0T,
    const float* __restrict__ Wf1T, const float* __restrict__ Wr1T,
    const float* __restrict__ WoT, const float* __restrict__ bf,
    const float* __restrict__ bo, float* __restrict__ out) {
  __shared__ float spk0[256], spk1[256];
  __shared__ int LA[256], LB[256];
  __shared__ int nA, nB;
  __shared__ float obuf[20];
  const int b = blockIdx.x;
  const int h = threadIdx.x;

  float m0 = 0.f, m1 = 0.f, s0self = 0.f, s1self = 0.f;
  const float bf1v = bf[256 + h];
  float omem = 0.f, ospk = 0.f, osum = 0.f, omot = 0.f;
  const float bov = (h < 20) ? bo[h] : 0.f;

  if (h == 0) { nA = 0; nB = 0; }
  __syncthreads();

  for (int t = 0; t < 50; ++t) {
    // ---- layer 0: m0 = m0*a*(1-s0) + ff0 + sum_{k in s0_old} Wr0T[k][h]
    float acc0 = ff0[((size_t)t * 512 + b) * 256 + h];
    {
      const int n = nA;
      int j = 0;
      for (; j + 4 <= n; j += 4) {
        const int k0 = LA[j], k1 = LA[j + 1], k2 = LA[j + 2], k3 = LA[j + 3];
        const float w0 = Wr0T[k0 * 256 + h], w1 = Wr0T[k1 * 256 + h];
        const float w2 = Wr0T[k2 * 256 + h], w3 = Wr0T[k3 * 256 + h];
        acc0 += (w0 + w1) + (w2 + w3);
      }
      for (; j < n; ++j) acc0 += Wr0T[LA[j] * 256 + h];
    }
    m0 = m0 * 0.8f * (1.f - s0self) + acc0;
    s0self = (m0 - 0.3f > 0.f) ? 1.f : 0.f;
    spk0[h] = s0self;
    __syncthreads();
    if (h < 64) {  // wave 0: compact s0_new -> LA
      int base = 0;
#pragma unroll
      for (int c = 0; c < 4; ++c) {
        const int k = c * 64 + h;
        const bool sp = spk0[k] > 0.f;
        const unsigned long long mk = __ballot(sp);
        const int pos = base + (int)__popcll(mk & ((1ull << h) - 1ull));
        if (sp) LA[pos] = k;
        base += (int)__popcll(mk);
      }
      if (h == 0) nA = base;
    }
    __syncthreads();
    // ---- layer 1: inputs s0_new (LA) and s1_old (LB)
    float acc1 = bf1v;
    {
      const int n = nA;
      int j = 0;
      for (; j + 4 <= n; j += 4) {
        const int k0 = LA[j], k1 = LA[j + 1], k2 = LA[j + 2], k3 = LA[j + 3];
        const float w0 = Wf1T[k0 * 256 + h], w1 = Wf1T[k1 * 256 + h];
        const float w2 = Wf1T[k2 * 256 + h], w3 = Wf1T[k3 * 256 + h];
        acc1 += (w0 + w1) + (w2 + w3);
      }
      for (; j < n; ++j) acc1 += Wf1T[LA[j] * 256 + h];
    }
    {
      const int n = nB;
      int j = 0;
      for (; j + 4 <= n; j += 4) {
        const int k0 = LB[j], k1 = LB[j + 1], k2 = LB[j + 2], k3 = LB[j + 3];
        const float w0 = Wr1T[k0 * 256 + h], w1 = Wr1T[k1 * 256 + h];
        const float w2 = Wr1T[k2 * 256 + h], w3 = Wr1T[k3 * 256 + h];
        acc1 += (w0 + w1) + (w2 + w3);
      }
      for (; j < n; ++j) acc1 += Wr1T[LB[j] * 256 + h];
    }
    m1 = m1 * 0.8f * (1.f - s1self) + acc1;
    s1self = (m1 - 0.3f > 0.f) ? 1.f : 0.f;
    spk1[h] = s1self;
    __syncthreads();
    if (h < 64) {  // wave 0: compact s1_new -> LB
      int base = 0;
#pragma unroll
      for (int c = 0; c < 4; ++c) {
        const int k = c * 64 + h;
        const bool sp = spk1[k] > 0.f;
        const unsigned long long mk = __ballot(sp);
        const int pos = base + (int)__popcll(mk & ((1ull << h) - 1ull));
        if (sp) LB[pos] = k;
        base += (int)__popcll(mk);
      }
      if (h == 0) nB = base;
    }
    __syncthreads();
    // ---- readout (20 workers)
    if (h < 20) {
      float oacc = bov;
      const int n = nB;
      for (int j = 0; j < n; ++j) oacc += WoT[LB[j] * 20 + h];
      omem = omem * 0.8f * (1.f - ospk) + oacc;
      ospk = (omem - 0.3f > 0.f) ? 1.f : 0.f;
      osum += ospk;
      obuf[h] = omem;
    }
    __syncthreads();
    if (h < 20) {  // stable softmax accumulate
      float mx = obuf[0];
      for (int j = 1; j < 20; ++j) mx = fmaxf(mx, obuf[j]);
      float sm = 0.f;
      for (int j = 0; j < 20; ++j) sm += expf(obuf[j] - mx);
      omot += expf(omem - mx) / sm;
    }
  }
  if (h < 20) {
    out[b * 20 + h] = osum / 50.0f;
    out[10240 + b * 20 + h] = omot;
  }
}

// ---------------------------------------------------------------------------
extern "C" void kernel_launch(void* const* d_in, const int* in_sizes, int n_in,
                              void* d_out, int out_size, void* d_ws, size_t ws_size,
                              hipStream_t stream) {
  const float* x  = (const float*)d_in[0];
  const float* Wd = (const float*)d_in[1];
  const float* bd = (const float*)d_in[2];
  const float* Wf = (const float*)d_in[3];
  const float* bf = (const float*)d_in[4];
  const float* Wr = (const float*)d_in[5];
  const float* Wo = (const float*)d_in[6];
  const float* bo = (const float*)d_in[7];
  float* out = (float*)d_out;
  float* ws  = (float*)d_ws;

  float* cur  = ws;                    // [25600][256], becomes ff0 in place
  float* Wr0T = ws + CUR_ELEMS;
  float* Wf1T = Wr0T + 65536;
  float* Wr1T = Wf1T + 65536;
  float* WoT  = Wr1T + 65536;

  hipLaunchKernelGGL(k0_transpose, dim3(789), dim3(256), 0, stream, Wf, Wr, Wo, ws);
  hipLaunchKernelGGL(k1_cur, dim3(8, 50), dim3(256), 0, stream, x, Wd, bd, cur);
  hipLaunchKernelGGL(k1b_ff0, dim3(400), dim3(256), 0, stream, Wf, bf, cur);
  hipLaunchKernelGGL(k2_scan, dim3(512), dim3(256), 0, stream, cur, Wr0T, Wf1T,
                     Wr1T, WoT, bf, bo, out);
}

// Round 3
// 983.370 us; speedup vs baseline: 1.1601x; 1.1601x over previous
//
#include <hip/hip_runtime.h>
#include <cstddef>

#define CUR_ELEMS (25600 * 256)   // [50*512][256] f32 scratch (cur, then ff0 in place)
#define WROWS 65792               // 257 rows * 256 (row 256 = zeros for list padding)

// ---------------------------------------------------------------------------
// K0: one-time weight transposes into workspace (k-major for sparse column
// sums), each with an extra all-zero row at index 256 (list-padding sink).
// ---------------------------------------------------------------------------
__global__ __launch_bounds__(256) void k0_transpose(
    const float* __restrict__ Wf, const float* __restrict__ Wr,
    const float* __restrict__ Wo, float* __restrict__ ws) {
  int tid = blockIdx.x * blockDim.x + threadIdx.x;
  float* Wr0T = ws + CUR_ELEMS;
  float* Wf1T = Wr0T + WROWS;
  float* Wr1T = Wf1T + WROWS;
  float* WoT  = Wr1T + WROWS;
  if (tid < WROWS) {
    int k = tid >> 8, h = tid & 255;
    Wr0T[tid] = (k < 256) ? Wr[h * 256 + k] : 0.f;
  } else if (tid < 2 * WROWS) {
    int i = tid - WROWS; int k = i >> 8, h = i & 255;
    Wf1T[i] = (k < 256) ? Wf[65536 + h * 256 + k] : 0.f;
  } else if (tid < 3 * WROWS) {
    int i = tid - 2 * WROWS; int k = i >> 8, h = i & 255;
    Wr1T[i] = (k < 256) ? Wr[65536 + h * 256 + k] : 0.f;
  } else if (tid < 3 * WROWS + 5140) {
    int i = tid - 3 * WROWS; int k = i / 20, j = i - k * 20;
    WoT[i] = (k < 256) ? Wo[j * 256 + k] : 0.f;
  }
}

// ---------------------------------------------------------------------------
// K1: cur[t][b][h] = sum_i x[b, t-d_i, :] . Wd[i][h][:]  + sum_i bd[i][h]
// 128(b) x 64(h) tiles -> 800 blocks (load balance vs 128x128's 400).
// 256 threads, 8x4 micro-tile, K-chunks of 16, per-tile delay skip.
// ---------------------------------------------------------------------------
__global__ __launch_bounds__(256) void k1_cur(
    const float* __restrict__ x, const float* __restrict__ Wd,
    const float* __restrict__ bd, float* __restrict__ cur) {
  __shared__ float As[16][132];   // [kk][b-row], +4 pad
  __shared__ float Bs[16][68];    // [kk][h-col], +4 pad
  const int t  = blockIdx.y;
  const int bt = blockIdx.x >> 2, ht = blockIdx.x & 3;
  const int b0 = bt * 128, h0 = ht * 64;
  const int tid = threadIdx.x;
  const int tx = tid & 15, ty = tid >> 4;      // h: tx*4, b: ty*8
  const int ra = tid & 127, halfa = tid >> 7;  // A staging
  const int rb = tid & 63,  kb = (tid >> 6) * 4;  // B staging

  float acc[8][4];
#pragma unroll
  for (int i = 0; i < 8; ++i)
#pragma unroll
    for (int j = 0; j < 4; ++j) acc[i][j] = 0.f;

  const int DEL[3] = {0, 16, 32};
#pragma unroll 1
  for (int di = 0; di < 3; ++di) {
    const int d = DEL[di];
    if (t < d) continue;
    const int tsrc = t - d;
    const float* Arow = x + ((size_t)(b0 + ra) * 50 + tsrc) * 700;
    const float* Brow = Wd + (size_t)di * 179200 + (size_t)(h0 + rb) * 700;
#pragma unroll 1
    for (int k0 = 0; k0 < 700; k0 += 16) {
      // stage A: 128 rows x 16 k = 8 floats/thread (two guarded float4)
#pragma unroll
      for (int e = 0; e < 2; ++e) {
        const int kk0 = halfa * 8 + e * 4;
        float4 av = (k0 + kk0 + 3 < 700) ? *(const float4*)(Arow + k0 + kk0)
                                         : make_float4(0.f, 0.f, 0.f, 0.f);
        As[kk0 + 0][ra] = av.x; As[kk0 + 1][ra] = av.y;
        As[kk0 + 2][ra] = av.z; As[kk0 + 3][ra] = av.w;
      }
      // stage B: 64 rows x 16 k = 4 floats/thread (one guarded float4)
      {
        float4 bv = (k0 + kb + 3 < 700) ? *(const float4*)(Brow + k0 + kb)
                                        : make_float4(0.f, 0.f, 0.f, 0.f);
        Bs[kb + 0][rb] = bv.x; Bs[kb + 1][rb] = bv.y;
        Bs[kb + 2][rb] = bv.z; Bs[kb + 3][rb] = bv.w;
      }
      __syncthreads();
#pragma unroll
      for (int kk = 0; kk < 16; ++kk) {
        const float4 a0 = *(const float4*)&As[kk][ty * 8];
        const float4 a1 = *(const float4*)&As[kk][ty * 8 + 4];
        const float4 bq = *(const float4*)&Bs[kk][tx * 4];
        const float ar[8] = {a0.x, a0.y, a0.z, a0.w, a1.x, a1.y, a1.z, a1.w};
        const float br[4] = {bq.x, bq.y, bq.z, bq.w};
#pragma unroll
        for (int rr = 0; rr < 8; ++rr)
#pragma unroll
          for (int cc = 0; cc < 4; ++cc) acc[rr][cc] += ar[rr] * br[cc];
      }
      __syncthreads();
    }
  }
  float bias[4];
#pragma unroll
  for (int c = 0; c < 4; ++c) {
    const int col = h0 + tx * 4 + c;
    bias[c] = bd[col] + bd[256 + col] + bd[512 + col];
  }
#pragma unroll
  for (int rr = 0; rr < 8; ++rr) {
    const int row = b0 + ty * 8 + rr;
    float* dst = cur + ((size_t)t * 512 + row) * 256 + h0 + tx * 4;
    float4 v = make_float4(acc[rr][0] + bias[0], acc[rr][1] + bias[1],
                           acc[rr][2] + bias[2], acc[rr][3] + bias[3]);
    *(float4*)dst = v;
  }
}

// ---------------------------------------------------------------------------
// K1b: ff0[m][h] = cur[m][:] . Wf0[h][:] + bf0[h], IN PLACE over cur.
// ---------------------------------------------------------------------------
__global__ __launch_bounds__(256) void k1b_ff0(
    const float* __restrict__ Wf, const float* __restrict__ bf,
    float* __restrict__ cur) {
  __shared__ float As[16][68];
  __shared__ float Bs[16][260];
  const int m0 = blockIdx.x * 64;
  const int tid = threadIdx.x;
  const int tx = tid & 15, ty = tid >> 4;
  const int lr = tid & 63, akk = (tid >> 6) * 4;

  float acc[4][16];
#pragma unroll
  for (int i = 0; i < 4; ++i)
#pragma unroll
    for (int j = 0; j < 16; ++j) acc[i][j] = 0.f;

#pragma unroll 1
  for (int k0 = 0; k0 < 256; k0 += 16) {
    float4 av = *(const float4*)(cur + (size_t)(m0 + lr) * 256 + k0 + akk);
    As[akk + 0][lr] = av.x; As[akk + 1][lr] = av.y;
    As[akk + 2][lr] = av.z; As[akk + 3][lr] = av.w;
#pragma unroll
    for (int e = 0; e < 4; ++e) {
      const int hh = e * 64 + lr;
      float4 bv = *(const float4*)(Wf + (size_t)hh * 256 + k0 + akk);
      Bs[akk + 0][hh] = bv.x; Bs[akk + 1][hh] = bv.y;
      Bs[akk + 2][hh] = bv.z; Bs[akk + 3][hh] = bv.w;
    }
    __syncthreads();
#pragma unroll
    for (int kk = 0; kk < 16; ++kk) {
      const float4 a = *(const float4*)&As[kk][ty * 4];
      const float ar[4] = {a.x, a.y, a.z, a.w};
#pragma unroll
      for (int q = 0; q < 4; ++q) {
        const float4 bq = *(const float4*)&Bs[kk][q * 64 + tx * 4];
        const float br[4] = {bq.x, bq.y, bq.z, bq.w};
#pragma unroll
        for (int rr = 0; rr < 4; ++rr)
#pragma unroll
          for (int cc = 0; cc < 4; ++cc)
            acc[rr][q * 4 + cc] += ar[rr] * br[cc];
      }
    }
    __syncthreads();
  }
  float bias[16];
#pragma unroll
  for (int q = 0; q < 4; ++q)
#pragma unroll
    for (int c = 0; c < 4; ++c) bias[q * 4 + c] = bf[q * 64 + tx * 4 + c];
#pragma unroll
  for (int rr = 0; rr < 4; ++rr) {
    float* dst = cur + (size_t)(m0 + ty * 4 + rr) * 256;
#pragma unroll
    for (int q = 0; q < 4; ++q) {
      float4 v = make_float4(acc[rr][q * 4 + 0] + bias[q * 4 + 0],
                             acc[rr][q * 4 + 1] + bias[q * 4 + 1],
                             acc[rr][q * 4 + 2] + bias[q * 4 + 2],
                             acc[rr][q * 4 + 3] + bias[q * 4 + 3]);
      *(float4*)(dst + q * 64 + tx * 4) = v;
    }
  }
}

// ---------------------------------------------------------------------------
// Sparse column-sum helpers. Lists are padded to a multiple of 16 with index
// 256 (zero row), so only the 16-deep batched loop runs -> 16 loads in
// flight per batch instead of 4 -> ~4x shorter latency chain.
// ---------------------------------------------------------------------------
__device__ __forceinline__ float sparse_sum16(const float* __restrict__ W,
                                              const int* L, int nP, int h) {
  float acc = 0.f;
  for (int j = 0; j < nP; j += 16) {
    float w[16];
#pragma unroll
    for (int u = 0; u < 16; ++u) w[u] = W[L[j + u] * 256 + h];
    float s0 = 0.f, s1 = 0.f, s2 = 0.f, s3 = 0.f;
#pragma unroll
    for (int u = 0; u < 16; u += 4) {
      s0 += w[u]; s1 += w[u + 1]; s2 += w[u + 2]; s3 += w[u + 3];
    }
    acc += (s0 + s1) + (s2 + s3);
  }
  return acc;
}

// Two interleaved streams: 32 loads in flight while both lists have work.
__device__ __forceinline__ float sparse_sum2x16(
    const float* __restrict__ WA, const int* LA, int nA,
    const float* __restrict__ WB, const int* LB, int nB, int h) {
  float acc = 0.f;
  int ja = 0, jb = 0;
  while (ja + 16 <= nA && jb + 16 <= nB) {
    float wa[16], wb[16];
#pragma unroll
    for (int u = 0; u < 16; ++u) wa[u] = WA[LA[ja + u] * 256 + h];
#pragma unroll
    for (int u = 0; u < 16; ++u) wb[u] = WB[LB[jb + u] * 256 + h];
    float s0 = 0.f, s1 = 0.f, s2 = 0.f, s3 = 0.f;
#pragma unroll
    for (int u = 0; u < 16; u += 4) {
      s0 += wa[u] + wb[u]; s1 += wa[u + 1] + wb[u + 1];
      s2 += wa[u + 2] + wb[u + 2]; s3 += wa[u + 3] + wb[u + 3];
    }
    acc += (s0 + s1) + (s2 + s3);
    ja += 16; jb += 16;
  }
  for (; ja + 16 <= nA; ja += 16) {
    float w[16];
#pragma unroll
    for (int u = 0; u < 16; ++u) w[u] = WA[LA[ja + u] * 256 + h];
    float s0 = 0.f, s1 = 0.f, s2 = 0.f, s3 = 0.f;
#pragma unroll
    for (int u = 0; u < 16; u += 4) {
      s0 += w[u]; s1 += w[u + 1]; s2 += w[u + 2]; s3 += w[u + 3];
    }
    acc += (s0 + s1) + (s2 + s3);
  }
  for (; jb + 16 <= nB; jb += 16) {
    float w[16];
#pragma unroll
    for (int u = 0; u < 16; ++u) w[u] = WB[LB[jb + u] * 256 + h];
    float s0 = 0.f, s1 = 0.f, s2 = 0.f, s3 = 0.f;
#pragma unroll
    for (int u = 0; u < 16; u += 4) {
      s0 += w[u]; s1 += w[u + 1]; s2 += w[u + 2]; s3 += w[u + 3];
    }
    acc += (s0 + s1) + (s2 + s3);
  }
  return acc;
}

// ---------------------------------------------------------------------------
// K2: 50-step recurrent scan. One block per batch row (512 blocks, 256 thr).
// 4 barriers/step; readout parallelized over 60 lanes of wave 0 (3 lanes per
// output class, shuffle-reduced) so readout+softmax are single-wave.
// ---------------------------------------------------------------------------
__global__ __launch_bounds__(256) void k2_scan(
    const float* __restrict__ ff0, const float* __restrict__ Wr0T,
    const float* __restrict__ Wf1T, const float* __restrict__ Wr1T,
    const float* __restrict__ WoT, const float* __restrict__ bf,
    const float* __restrict__ bo, float* __restrict__ out) {
  __shared__ float spk0[256], spk1[256];
  __shared__ int LA[272], LB[272];   // padded to %16 with sink index 256
  __shared__ int nA_s, nB_s;
  __shared__ float obuf[20];
  const int b = blockIdx.x;
  const int h = threadIdx.x;

  float m0 = 0.f, m1 = 0.f, s0self = 0.f, s1self = 0.f;
  const float bf1v = bf[256 + h];
  float omem = 0.f, ospk = 0.f, osum = 0.f, omot = 0.f;
  const float bov = (h < 20) ? bo[h] : 0.f;
  // readout mapping: lanes 0..59 of wave 0 -> (o = h/3, c = h%3)
  const int ro = h / 3, rc = h - ro * 3;

  if (h == 0) { nA_s = 0; nB_s = 0; }
  __syncthreads();

  const float* ffp = ff0 + (size_t)b * 256 + h;
  for (int t = 0; t < 50; ++t) {
    // ---- layer 0
    float acc0 = ffp[(size_t)t * 512 * 256] + sparse_sum16(Wr0T, LA, nA_s, h);
    m0 = m0 * 0.8f * (1.f - s0self) + acc0;
    s0self = (m0 - 0.3f > 0.f) ? 1.f : 0.f;
    spk0[h] = s0self;
    __syncthreads();                                   // B1
    if (h < 64) {  // wave 0: compact s0_new -> LA (+pad to %16 with 256)
      int base = 0;
#pragma unroll
      for (int c = 0; c < 4; ++c) {
        const int k = c * 64 + h;
        const bool sp = spk0[k] > 0.f;
        const unsigned long long mk = __ballot(sp);
        const int pos = base + (int)__popcll(mk & ((1ull << h) - 1ull));
        if (sp) LA[pos] = k;
        base += (int)__popcll(mk);
      }
      const int pad = (-base) & 15;
      if (h < pad) LA[base + h] = 256;
      if (h == 0) nA_s = base + pad;
    }
    __syncthreads();                                   // B2
    // ---- layer 1: s0_new (LA) @ Wf1 + s1_old (LB) @ Wr1, interleaved
    float acc1 = bf1v + sparse_sum2x16(Wf1T, LA, nA_s, Wr1T, LB, nB_s, h);
    m1 = m1 * 0.8f * (1.f - s1self) + acc1;
    s1self = (m1 - 0.3f > 0.f) ? 1.f : 0.f;
    spk1[h] = s1self;
    __syncthreads();                                   // B3
    if (h < 64) {  // wave 0: compact s1_new -> LB (+pad)
      int base = 0;
#pragma unroll
      for (int c = 0; c < 4; ++c) {
        const int k = c * 64 + h;
        const bool sp = spk1[k] > 0.f;
        const unsigned long long mk = __ballot(sp);
        const int pos = base + (int)__popcll(mk & ((1ull << h) - 1ull));
        if (sp) LB[pos] = k;
        base += (int)__popcll(mk);
      }
      const int pad = (-base) & 15;
      if (h < pad) LB[base + h] = 256;
      if (h == 0) nB_s = base + pad;
    }
    __syncthreads();                                   // B4
    // ---- readout: wave 0 only (lanes 0..59 accumulate, 0..19 hold state)
    if (h < 64) {
      const int nP = nB_s;
      float v = 0.f;
      if (h < 60) {
        int j = rc;
        while (j + 21 < nP) {  // 8 strided loads per batch
          float w[8];
#pragma unroll
          for (int u = 0; u < 8; ++u) w[u] = WoT[LB[j + u * 3] * 20 + ro];
          v += ((w[0] + w[1]) + (w[2] + w[3])) + ((w[4] + w[5]) + (w[6] + w[7]));
          j += 24;
        }
        for (; j < nP; j += 3) v += WoT[LB[j] * 20 + ro];
      }
      // 3-lane reduction: shuffle the ORIGINAL v twice (NOT a 2-step
      // butterfly, which would absorb lane 3k+3's partial — round-2 bug).
      const float v1 = __shfl_down(v, 1);
      const float v2 = __shfl_down(v, 2);
      v += v1 + v2;
      if (rc == 0 && ro < 20) obuf[ro] = v;  // same-wave LDS, no barrier
      if (h < 20) {
        const float oacc = bov + obuf[h];
        omem = omem * 0.8f * (1.f - ospk) + oacc;
        ospk = (omem - 0.3f > 0.f) ? 1.f : 0.f;
        osum += ospk;
        obuf[h] = omem;
      }
      if (h < 20) {  // stable softmax accumulate (same-wave LDS)
        float mx = obuf[0];
        for (int j = 1; j < 20; ++j) mx = fmaxf(mx, obuf[j]);
        float sm = 0.f;
        for (int j = 0; j < 20; ++j) sm += expf(obuf[j] - mx);
        omot += expf(omem - mx) / sm;
      }
    }
  }
  if (h < 20) {
    out[b * 20 + h] = osum / 50.0f;
    out[10240 + b * 20 + h] = omot;
  }
}

// ---------------------------------------------------------------------------
extern "C" void kernel_launch(void* const* d_in, const int* in_sizes, int n_in,
                              void* d_out, int out_size, void* d_ws, size_t ws_size,
                              hipStream_t stream) {
  const float* x  = (const float*)d_in[0];
  const float* Wd = (const float*)d_in[1];
  const float* bd = (const float*)d_in[2];
  const float* Wf = (const float*)d_in[3];
  const float* bf = (const float*)d_in[4];
  const float* Wr = (const float*)d_in[5];
  const float* Wo = (const float*)d_in[6];
  const float* bo = (const float*)d_in[7];
  float* out = (float*)d_out;
  float* ws  = (float*)d_ws;

  float* cur  = ws;                    // [25600][256], becomes ff0 in place
  float* Wr0T = ws + CUR_ELEMS;
  float* Wf1T = Wr0T + WROWS;
  float* Wr1T = Wf1T + WROWS;
  float* WoT  = Wr1T + WROWS;

  hipLaunchKernelGGL(k0_transpose, dim3(792), dim3(256), 0, stream, Wf, Wr, Wo, ws);
  hipLaunchKernelGGL(k1_cur, dim3(16, 50), dim3(256), 0, stream, x, Wd, bd, cur);
  hipLaunchKernelGGL(k1b_ff0, dim3(400), dim3(256), 0, stream, Wf, bf, cur);
  hipLaunchKernelGGL(k2_scan, dim3(512), dim3(256), 0, stream, cur, Wr0T, Wf1T,
                     Wr1T, WoT, bf, bo, out);
}